// Round 13
// baseline (219.093 us; speedup 1.0000x reference)
//
#include <hip/hip_runtime.h>
#include <cmath>

#ifndef M_PI
#define M_PI 3.14159265358979323846
#endif

typedef float v2f __attribute__((ext_vector_type(2)));
typedef float v4f __attribute__((ext_vector_type(4)));
typedef _Float16 h2 __attribute__((ext_vector_type(2)));

constexpr int Dn = 200;
constexpr int DD = Dn * Dn;        // 40000
constexpr int NC = Dn * Dn * Dn;   // 8,000,000
constexpr int TPR = 25;            // threads per row (8 cells each)
constexpr int RPB = 10;            // rows per block (250 live threads)
constexpr int NBLK = (Dn * Dn) / RPB;  // 4000, divisible by 8 -> bijective XCD swizzle
constexpr float THR = 0.0100001f;  // exact-path threshold (f32)
// f16 screen threshold: RTZ cvt err<0.0078/input (pos<=10) -> sq~ < 0.0165 when sq<0.01
#define HTHR ((_Float16)0.017f)

// compile-time component selectors (fold to subregister access under full unroll)
#define C4(v,c) ((c)==0?(v).x:(c)==1?(v).y:(c)==2?(v).z:(v).w)
#define WK(L,A,B,R,k) ((k)==0?(L).x:(k)==1?(L).y: \
                       ((k)>=2&&(k)<=5)?C4(A,(k)-2): \
                       ((k)>=6&&(k)<=9)?C4(B,(k)-6): \
                       ((k)==10?(R).x:(R).y))

__device__ __forceinline__ h2 cvtpk(float a, float b) {
    return __builtin_bit_cast(h2, __builtin_amdgcn_cvt_pkrtz(a, b));
}

__global__ __launch_bounds__(256) void dem_step_kernel(
    const float* __restrict__ gx, const float* __restrict__ gy, const float* __restrict__ gz,
    const float* __restrict__ gvx, const float* __restrict__ gvy, const float* __restrict__ gvz,
    const float* __restrict__ gm, float* __restrict__ out,
    float ETAf, float dtOverPm, float gravTerm)
{
    const int t = threadIdx.x;
    if (t >= TPR * RPB) return;

    const int bid = blockIdx.x;
    const int sb = (bid & 7) * (NBLK / 8) + (bid >> 3);   // XCD-contiguous z-slabs

    const int rowid = sb * RPB + t / TPR;
    const int x0 = (t % TPR) * 8;
    const int zi = rowid / Dn;
    const int yj = rowid % Dn;
    const int cbase = rowid * Dn + x0;
    const int xl = (x0 == 0) ? (Dn - 2) : (x0 - 2);
    const int xr = (x0 == Dn - 8) ? 0 : (x0 + 8);

    // ---- center positions (f32) ----
    const v4f Xa = *reinterpret_cast<const v4f*>(gx + cbase);
    const v4f Xb = *reinterpret_cast<const v4f*>(gx + cbase + 4);
    const v4f Ya = *reinterpret_cast<const v4f*>(gy + cbase);
    const v4f Yb = *reinterpret_cast<const v4f*>(gy + cbase + 4);
    const v4f Za = *reinterpret_cast<const v4f*>(gz + cbase);
    const v4f Zb = *reinterpret_cast<const v4f*>(gz + cbase + 4);

    // ---- f16 center packs (RTZ): even pairs {0,1},{2,3},{4,5},{6,7}; odd {1,2},{3,4},{5,6} ----
    const h2 hXe[4] = {cvtpk(Xa.x,Xa.y), cvtpk(Xa.z,Xa.w), cvtpk(Xb.x,Xb.y), cvtpk(Xb.z,Xb.w)};
    const h2 hYe[4] = {cvtpk(Ya.x,Ya.y), cvtpk(Ya.z,Ya.w), cvtpk(Yb.x,Yb.y), cvtpk(Yb.z,Yb.w)};
    const h2 hZe[4] = {cvtpk(Za.x,Za.y), cvtpk(Za.z,Za.w), cvtpk(Zb.x,Zb.y), cvtpk(Zb.z,Zb.w)};
    const h2 hXo[3] = {cvtpk(Xa.y,Xa.z), cvtpk(Xa.w,Xb.x), cvtpk(Xb.y,Xb.z)};
    const h2 hYo[3] = {cvtpk(Ya.y,Ya.z), cvtpk(Ya.w,Yb.x), cvtpk(Yb.y,Yb.z)};
    const h2 hZo[3] = {cvtpk(Za.y,Za.z), cvtpk(Za.w,Zb.x), cvtpk(Zb.y,Zb.z)};

    // wrapped y row bases (compile-time indexed after unroll)
    int ybs[5];
    #pragma unroll
    for (int o = 0; o < 5; ++o) {
        int yy = yj + o - 2; yy += (yy < 0) ? Dn : 0; yy -= (yy >= Dn) ? Dn : 0;
        ybs[o] = yy * Dn;
    }

    float fxa[8] = {0,0,0,0,0,0,0,0};
    float fya[8] = {0,0,0,0,0,0,0,0};
    float fza[8] = {0,0,0,0,0,0,0,0};

    for (int i2 = 0; i2 < 5; ++i2) {
        int zz = zi + i2 - 2; zz += (zz < 0) ? Dn : 0; zz -= (zz >= Dn) ? Dn : 0;
        const int zbase = zz * DD;
        const bool zc = (i2 == 2);
        #pragma unroll
        for (int i3 = 0; i3 < 5; ++i3) {
            const int rowb = zbase + ybs[i3];
            const bool ctr = zc && (i3 == 2);     // i3 compile-time; zc uniform

            // 12-float f32 windows: f2 + f4 + f4 + f2 per array
            const v2f wxL = *reinterpret_cast<const v2f*>(gx + rowb + xl);
            const v4f wxA = *reinterpret_cast<const v4f*>(gx + rowb + x0);
            const v4f wxB = *reinterpret_cast<const v4f*>(gx + rowb + x0 + 4);
            const v2f wxR = *reinterpret_cast<const v2f*>(gx + rowb + xr);
            const v2f wyL = *reinterpret_cast<const v2f*>(gy + rowb + xl);
            const v4f wyA = *reinterpret_cast<const v4f*>(gy + rowb + x0);
            const v4f wyB = *reinterpret_cast<const v4f*>(gy + rowb + x0 + 4);
            const v2f wyR = *reinterpret_cast<const v2f*>(gy + rowb + xr);
            const v2f wzL = *reinterpret_cast<const v2f*>(gz + rowb + xl);
            const v4f wzA = *reinterpret_cast<const v4f*>(gz + rowb + x0);
            const v4f wzB = *reinterpret_cast<const v4f*>(gz + rowb + x0 + 4);
            const v2f wzR = *reinterpret_cast<const v2f*>(gz + rowb + xr);

            // f16 natural window pairs hW[j] = {w[2j], w[2j+1]}
            const h2 hx[6] = {cvtpk(wxL.x,wxL.y), cvtpk(wxA.x,wxA.y), cvtpk(wxA.z,wxA.w),
                              cvtpk(wxB.x,wxB.y), cvtpk(wxB.z,wxB.w), cvtpk(wxR.x,wxR.y)};
            const h2 hy[6] = {cvtpk(wyL.x,wyL.y), cvtpk(wyA.x,wyA.y), cvtpk(wyA.z,wyA.w),
                              cvtpk(wyB.x,wyB.y), cvtpk(wyB.z,wyB.w), cvtpk(wyR.x,wyR.y)};
            const h2 hz[6] = {cvtpk(wzL.x,wzL.y), cvtpk(wzA.x,wzA.y), cvtpk(wzA.z,wzA.w),
                              cvtpk(wzB.x,wzB.y), cvtpk(wzB.z,wzB.w), cvtpk(wzR.x,wzR.y)};

            // ---- packed f16 screen: 18 units, 3 rotating half2 min accumulators ----
            h2 mm[3] = {{(_Float16)30000.0f, (_Float16)30000.0f},
                        {(_Float16)30000.0f, (_Float16)30000.0f},
                        {(_Float16)30000.0f, (_Float16)30000.0f}};
            #define HU(HX, HY, HZ, J, AI) { \
                const h2 _dx = (HX) - hx[J]; \
                const h2 _dy = (HY) - hy[J]; \
                const h2 _dz = (HZ) - hz[J]; \
                const h2 _s = _dx*_dx + _dy*_dy + _dz*_dz; \
                mm[AI] = __builtin_elementwise_min(_s, mm[AI]); }

            #pragma unroll
            for (int e = 0; e < 4; ++e) {              // even packs, o=0 and o=4
                HU(hXe[e], hYe[e], hZe[e], e,     (e) % 3)
                HU(hXe[e], hYe[e], hZe[e], e + 2, (e + 1) % 3)
            }
            if (!ctr) {                                 // even packs, o=2 (self column)
                #pragma unroll
                for (int e = 0; e < 4; ++e)
                    HU(hXe[e], hYe[e], hZe[e], e + 1, (e + 2) % 3)
            }
            #pragma unroll
            for (int d = 0; d < 3; ++d) {              // odd packs, o=1 and o=3
                HU(hXo[d], hYo[d], hZo[d], d + 1, (d) % 3)
                HU(hXo[d], hYo[d], hZo[d], d + 2, (d + 2) % 3)
            }
            #undef HU

            // 4 edge pairs in f32 (cell0 k=1,3; cell7 k=8,10)
            float mmE;
            {
                float dx = Xa.x - wxL.y, dy = Ya.x - wyL.y, dz = Za.x - wzL.y;
                const float e0 = fmaf(dz, dz, fmaf(dy, dy, dx * dx));
                dx = Xa.x - wxA.y; dy = Ya.x - wyA.y; dz = Za.x - wzA.y;
                const float e1 = fmaf(dz, dz, fmaf(dy, dy, dx * dx));
                dx = Xb.w - wxB.z; dy = Yb.w - wyB.z; dz = Zb.w - wzB.z;
                const float e2 = fmaf(dz, dz, fmaf(dy, dy, dx * dx));
                dx = Xb.w - wxR.x; dy = Yb.w - wyR.x; dz = Zb.w - wzR.x;
                const float e3 = fmaf(dz, dz, fmaf(dy, dy, dx * dx));
                mmE = fminf(fminf(e0, e1), fminf(e2, e3));
            }

            const h2 hmt = __builtin_elementwise_min(mm[0], __builtin_elementwise_min(mm[1], mm[2]));

            // ---- rare slow path (~2.2%/wave-row): full exact f32 reference math ----
            if (hmt.x < HTHR || hmt.y < HTHR || mmE < THR) {
                #pragma unroll
                for (int c = 0; c < 8; ++c) {
                    const float Xc = (c < 4) ? C4(Xa, c) : C4(Xb, c - 4);
                    const float Yc = (c < 4) ? C4(Ya, c) : C4(Yb, c - 4);
                    const float Zc = (c < 4) ? C4(Za, c) : C4(Zb, c - 4);
                    #pragma unroll
                    for (int o = 0; o < 5; ++o) {
                        const int k = c + o;
                        const float dx = Xc - WK(wxL, wxA, wxB, wxR, k);
                        const float dy = Yc - WK(wyL, wyA, wyB, wyR, k);
                        const float dz = Zc - WK(wzL, wzA, wzB, wzR, k);
                        const float sq = dx*dx + dy*dy + dz*dz;
                        if (sq < THR) {
                            const float dist = sqrtf(sq);
                            if (dist < 0.1f) {
                                const float d = fmaxf(dist, 1e-4f);
                                int nxi = x0 + c + o - 2;
                                nxi += (nxi < 0) ? Dn : 0;
                                nxi -= (nxi >= Dn) ? Dn : 0;
                                const int gi = rowb + nxi;
                                const float dvx = gvx[cbase + c] - gvx[gi];
                                const float dvy = gvy[cbase + c] - gvy[gi];
                                const float dvz = gvz[cbase + c] - gvz[gi];
                                const float vn = (dvx*dx + dvy*dy + dvz*dz) / d;
                                const float coef = 2.0f * (600000.0f*(dist - 0.1f) + ETAf*vn) / d;
                                fxa[c] += coef * dx;
                                fya[c] += coef * dy;
                                fza[c] += coef * dz;
                            }
                        }
                    }
                }
            }
        }
    }

    // ---- velocities + mask loaded only now (frees VGPRs during main loop) ----
    const v4f VXa = *reinterpret_cast<const v4f*>(gvx + cbase);
    const v4f VXb = *reinterpret_cast<const v4f*>(gvx + cbase + 4);
    const v4f VYa = *reinterpret_cast<const v4f*>(gvy + cbase);
    const v4f VYb = *reinterpret_cast<const v4f*>(gvy + cbase + 4);
    const v4f VZa = *reinterpret_cast<const v4f*>(gvz + cbase);
    const v4f VZb = *reinterpret_cast<const v4f*>(gvz + cbase + 4);
    const v4f Ma  = *reinterpret_cast<const v4f*>(gm  + cbase);
    const v4f Mb  = *reinterpret_cast<const v4f*>(gm  + cbase + 4);

    float ox[8], oy[8], oz[8], ovx[8], ovy[8], ovz[8];
    #pragma unroll
    for (int c = 0; c < 8; ++c) {
        const float X = (c < 4) ? C4(Xa, c) : C4(Xb, c - 4);
        const float Y = (c < 4) ? C4(Ya, c) : C4(Yb, c - 4);
        const float Z = (c < 4) ? C4(Za, c) : C4(Zb, c - 4);
        const float VX = (c < 4) ? C4(VXa, c) : C4(VXb, c - 4);
        const float VY = (c < 4) ? C4(VYa, c) : C4(VYb, c - 4);
        const float VZ = (c < 4) ? C4(VZa, c) : C4(VZb, c - 4);
        const float M  = (c < 4) ? C4(Ma,  c) : C4(Mb,  c - 4);

        float fxb = 0.f, fyb = 0.f, fzb = 0.f;
        if (X > 0.1f && X < 0.15f) fxb = 600000.0f * (0.15f - X) - ETAf * VX;
        if (X > 9.9f)              fxb = -600000.0f * (((X - 10.0f) + 0.05f) + 0.05f) - ETAf * VX;
        if (Y > 0.1f && Y < 0.15f) fyb = 600000.0f * (0.15f - Y) - ETAf * VY;
        if (Y > 9.9f)              fyb = -600000.0f * (((Y - 10.0f) + 0.05f) + 0.05f) - ETAf * VY;
        if (Z > 0.1f && Z < 0.15f) fzb = 600000.0f * (0.15f - Z) - ETAf * VZ;
        if (Z > 9.9f)              fzb = -600000.0f * (((Z - 10.0f) + 0.05f) + 0.05f) - ETAf * VZ;

        const float am = dtOverPm * M;
        ovx[c] = VX + am * ((-fxa[c]) + fxb);
        ovy[c] = VY + am * ((-fya[c]) + fyb);
        ovz[c] = VZ + am * ((gravTerm - fza[c]) + fzb);
        ox[c] = X + 1e-4f * ovx[c];
        oy[c] = Y + 1e-4f * ovy[c];
        oz[c] = Z + 1e-4f * ovz[c];
    }

    #define ST(arr, base) \
        __builtin_nontemporal_store((v4f){(arr)[0],(arr)[1],(arr)[2],(arr)[3]}, \
                                    reinterpret_cast<v4f*>(out + (base) + cbase)); \
        __builtin_nontemporal_store((v4f){(arr)[4],(arr)[5],(arr)[6],(arr)[7]}, \
                                    reinterpret_cast<v4f*>(out + (base) + cbase + 4));
    ST(ox,  0L * NC)
    ST(oy,  1L * NC)
    ST(oz,  2L * NC)
    ST(ovx, 3L * NC)
    ST(ovy, 4L * NC)
    ST(ovz, 5L * NC)
    #undef ST
}

extern "C" void kernel_launch(void* const* d_in, const int* in_sizes, int n_in,
                              void* d_out, int out_size, void* d_ws, size_t ws_size,
                              hipStream_t stream) {
    const float* gx  = (const float*)d_in[0];
    const float* gy  = (const float*)d_in[1];
    const float* gz  = (const float*)d_in[2];
    const float* gvx = (const float*)d_in[3];
    const float* gvy = (const float*)d_in[4];
    const float* gvz = (const float*)d_in[5];
    const float* gm  = (const float*)d_in[6];
    float* out = (float*)d_out;

    const double KN  = 600000.0;
    const double PM  = 4.0 / 3.0 * 3.1415 * std::pow(0.05, 3) * 2700.0;
    const double alpha = -std::log(0.5) / M_PI;
    const double gamma = alpha / std::sqrt(alpha * alpha + 1.0);
    const double ETA = 2.0 * gamma * std::sqrt(KN * PM);

    const float ETAf     = (float)ETA;
    const float dtOverPm = (float)(0.0001 / PM);
    const float gravTerm = (float)(-9.8 * PM);

    dem_step_kernel<<<NBLK, 256, 0, stream>>>(gx, gy, gz, gvx, gvy, gvz, gm, out,
                                              ETAf, dtOverPm, gravTerm);
}